// Round 3
// baseline (426.187 us; speedup 1.0000x reference)
//
#include <hip/hip_runtime.h>

#define BIG_Z_F 1000000.0f
#define N_MESH 8

// ---------------------------------------------------------------------------
// Kernel A: per-pixel cross-mesh reduction. Reads the 8 z values, computes
// covered-count + argmin (first-win tie, matches jnp.argmin), writes the
// per-mesh mask/zb outputs and a 1-byte winner code for kernel B:
//   win = dup0 ? argmin_mesh : 0xFF   (0xFF => no duplicates at this pixel)
// ---------------------------------------------------------------------------
__global__ __launch_bounds__(256) void raster_reduce(
    const float* __restrict__ zbuf,     // (N,HW)
    float* __restrict__ maskO,          // (N,HW)
    float* __restrict__ zbO,            // (N,HW)
    unsigned char* __restrict__ win,    // (HW) ws
    const int* __restrict__ mdp,        // scalar mask_duplicate
    int HW)
{
    const int pix = blockIdx.x * blockDim.x + threadIdx.x;
    if (pix >= HW) return;
    const int md = *mdp;

    float z[N_MESH];
    int count = 0;
    float best = __builtin_inff();
    int bidx = 0;
    #pragma unroll
    for (int n = 0; n < N_MESH; ++n) {
        const float zv = __builtin_nontemporal_load(&zbuf[n * HW + pix]);
        z[n] = zv;
        count += (zv > -1.0f) ? 1 : 0;
        const float t = (zv < 0.0f) ? BIG_Z_F : zv;
        if (t < best) { best = t; bidx = n; }   // strict < => first-win tie
    }
    const bool dup0 = (count > 1);

    #pragma unroll
    for (int n = 0; n < N_MESH; ++n) {
        const int idx = n * HW + pix;
        const bool dup = dup0 && ((md != 0) || (n != bidx));
        __builtin_nontemporal_store((z[n] >= 0.0f) ? 1.0f : 0.0f, &maskO[idx]);
        __builtin_nontemporal_store(dup ? -1.0f : z[n], &zbO[idx]);
    }
    win[pix] = dup0 ? (unsigned char)bidx : (unsigned char)0xFF;
}

// ---------------------------------------------------------------------------
// Kernel B: per-(mesh,pixel). 8x the parallelism of the old fused kernel and
// small register footprint -> full occupancy to hide the ~310 MB of streaming
// stores. Gather + interpolation predicated on valid (~1/8 of entries).
// ---------------------------------------------------------------------------
__global__ __launch_bounds__(256) void raster_interp(
    const int*   __restrict__ p2f,      // (N,HW)
    const float* __restrict__ bary,     // (N,HW,3)
    const float* __restrict__ dists,    // (N,HW)
    const float* __restrict__ fmem,     // (F,3,C)
    const unsigned char* __restrict__ win, // (HW)
    const int*   __restrict__ mdp,      // scalar mask_duplicate
    float* __restrict__ out_map,        // (N,C,HW)
    float* __restrict__ pO,             // (N,HW)
    float* __restrict__ dO,             // (N,HW)
    float* __restrict__ bcO,            // (N,HW,3)
    int*   __restrict__ faceflag,       // (F) ws, pre-zeroed
    int HW, int C)
{
    const int pix = blockIdx.x * blockDim.x + threadIdx.x;
    if (pix >= HW) return;
    const int n   = blockIdx.y;
    const int idx = n * HW + pix;
    const int md  = *mdp;

    const unsigned char w = win[pix];
    const bool dup = (w != 0xFF) && ((md != 0) || (n != (int)w));

    // Unconditional streaming loads + value select (loads stay fully
    // coalesced; predicating them wouldn't reduce cache lines touched).
    const int   praw = __builtin_nontemporal_load(&p2f[idx]);
    const float drw  = __builtin_nontemporal_load(&dists[idx]);
    const float* bp  = bary + (size_t)idx * 3;
    const float b0r  = __builtin_nontemporal_load(bp + 0);
    const float b1r  = __builtin_nontemporal_load(bp + 1);
    const float b2r  = __builtin_nontemporal_load(bp + 2);

    const int   p  = dup ? -1 : praw;
    const float b0 = dup ? -1.0f : b0r;
    const float b1 = dup ? -1.0f : b1r;
    const float b2 = dup ? -1.0f : b2r;

    __builtin_nontemporal_store((float)p, &pO[idx]);
    __builtin_nontemporal_store(dup ? -1.0f : drw, &dO[idx]);
    float* bo = bcO + (size_t)idx * 3;
    __builtin_nontemporal_store(b0, bo + 0);
    __builtin_nontemporal_store(b1, bo + 1);
    __builtin_nontemporal_store(b2, bo + 2);

    const bool valid = (p >= 0);
    if (valid) faceflag[p] = 1;         // benign race: all store 1

    const float* a = fmem + (size_t)(valid ? p : 0) * 3 * C;
    #pragma unroll
    for (int c4 = 0; c4 < 32; c4 += 4) {    // C == 32
        float r0 = 0.0f, r1 = 0.0f, r2 = 0.0f, r3 = 0.0f;
        if (valid) {
            const float4 a0 = *(const float4*)(a + c4);
            const float4 a1 = *(const float4*)(a + C + c4);
            const float4 a2 = *(const float4*)(a + 2 * C + c4);
            r0 = b0 * a0.x + b1 * a1.x + b2 * a2.x;
            r1 = b0 * a0.y + b1 * a1.y + b2 * a2.y;
            r2 = b0 * a0.z + b1 * a1.z + b2 * a2.z;
            r3 = b0 * a0.w + b1 * a1.w + b2 * a2.w;
        }
        const int obase = (n * C + c4) * HW + pix;
        __builtin_nontemporal_store(r0, &out_map[obase + 0 * HW]);
        __builtin_nontemporal_store(r1, &out_map[obase + 1 * HW]);
        __builtin_nontemporal_store(r2, &out_map[obase + 2 * HW]);
        __builtin_nontemporal_store(r3, &out_map[obase + 3 * HW]);
    }
}

// Scatter vertex visibility from face-visibility flags.
__global__ __launch_bounds__(256) void vert_vis(
    const int* __restrict__ faceflag,
    const int* __restrict__ pfaces,     // (F,3)
    float* __restrict__ vv,             // (V), pre-zeroed
    int F)
{
    const int f = blockIdx.x * blockDim.x + threadIdx.x;
    if (f >= F) return;
    if (faceflag[f]) {
        vv[pfaces[f * 3 + 0]] = 1.0f;
        vv[pfaces[f * 3 + 1]] = 1.0f;
        vv[pfaces[f * 3 + 2]] = 1.0f;
    }
}

extern "C" void kernel_launch(void* const* d_in, const int* in_sizes, int n_in,
                              void* d_out, int out_size, void* d_ws, size_t ws_size,
                              hipStream_t stream) {
    const float* zbuf   = (const float*)d_in[0];
    const int*   p2f    = (const int*)  d_in[1];
    const float* bary   = (const float*)d_in[2];
    const float* dists  = (const float*)d_in[3];
    const float* fmem   = (const float*)d_in[4];
    const int*   pfaces = (const int*)  d_in[5];
    // d_in[6] = num_verts (device scalar; V derived from out_size instead)
    const int*   mdp    = (const int*)  d_in[7];

    const long long P  = in_sizes[0];        // N*H*W*K = 2097152
    const int HW = (int)(P / N_MESH);        // 262144 pixels
    const int F3 = in_sizes[5];              // F*3
    const int F  = F3 / 3;                   // 20000
    const int C  = in_sizes[4] / F3;         // 32
    const int V  = (int)((long long)out_size - P * C - 7 * P);  // 10002

    float* out     = (float*)d_out;
    float* out_map = out;                    // P*C
    float* vv      = out_map + P * C;        // V
    float* maskO   = vv + V;                 // P
    float* zbO     = maskO + P;              // P
    float* pO      = zbO + P;                // P
    float* dO      = pO + P;                 // P
    float* bcO     = dO + P;                 // 3P

    int* faceflag      = (int*)d_ws;                 // F ints
    unsigned char* win = (unsigned char*)(faceflag + F); // HW bytes

    hipMemsetAsync(faceflag, 0, (size_t)F * sizeof(int), stream);
    hipMemsetAsync(vv, 0, (size_t)V * sizeof(float), stream);

    const int blocks = (HW + 255) / 256;

    raster_reduce<<<dim3(blocks), dim3(256), 0, stream>>>(
        zbuf, maskO, zbO, win, mdp, HW);

    raster_interp<<<dim3(blocks, N_MESH), dim3(256), 0, stream>>>(
        p2f, bary, dists, fmem, win, mdp,
        out_map, pO, dO, bcO, faceflag, HW, C);

    vert_vis<<<dim3((F + 255) / 256), dim3(256), 0, stream>>>(
        faceflag, pfaces, vv, F);
}